// Round 6
// baseline (419.833 us; speedup 1.0000x reference)
//
#include <hip/hip_runtime.h>
#include <hip/hip_cooperative_groups.h>

namespace cg = cooperative_groups;

// Problem constants (match reference setup_inputs)
#define Bn 8
#define Nn 131072
#define Cn 20
#define Kn 20

#define THREADS 256
#define GRID 1024                              // 4 blocks/CU -> co-resident for coop launch
#define BLOCKS_PER_BATCH (GRID / Bn)           // 128
#define CHUNK (Nn / BLOCKS_PER_BATCH)          // 1024 points per block
#define EPB (CHUNK / THREADS)                  // 4 per thread

// LDS bin replication: 8 copies indexed by lane&7, field-major with pad.
// acc[r][f*21 + k]; stride 84 floats -> replica bank offsets 20r mod 32
// = {0,20,8,28,16,4,24,12}, all distinct.
#define NREP 8
#define RSTRIDE 84

// ws layout (floats). Zeroed in-kernel (block 0) before first grid.sync.
#define WS_SEG 0                      // [640): x,y,z,count per (b,k) (atomics, 640 addrs)
#define WS_SEMP 640                   // [GRID) per-block sem partials (plain stores)
#define WS_CSVP (WS_SEMP + GRID)      // [GRID) per-block csv partials (plain stores)

__global__ void __launch_bounds__(THREADS, 4) loss_fused(
    const float* __restrict__ points,
    const float* __restrict__ sem,
    const float* __restrict__ pcsv,
    const int* __restrict__ label,
    float* __restrict__ ws,
    float* __restrict__ out) {
    cg::grid_group grid = cg::this_grid();

    __shared__ float acc[NREP][RSTRIDE];
    __shared__ float wsum[4];
    __shared__ float ctr[Kn][3];

    const int tid  = threadIdx.x;
    const int wave = tid >> 6;
    const int lane = tid & 63;
    const int rep  = lane & (NREP - 1);
    const int bid  = blockIdx.x;
    const int b    = bid / BLOCKS_PER_BATCH;
    const int n0   = (bid % BLOCKS_PER_BATCH) * CHUNK;

    // ---- phase 0: zero LDS bins (all blocks) + global bins (block 0) ----
    for (int i = tid; i < NREP * RSTRIDE; i += THREADS) ((float*)acc)[i] = 0.0f;
    if (bid == 0) {
        for (int i = tid; i < Bn * Kn * 4; i += THREADS) ws[WS_SEG + i] = 0.0f;
    }
    __syncthreads();
    grid.sync();   // global bins zeroed before any atomicAdd

    // ---- phase 1: sem gather-sum + per-(b,k) point sums & counts ----
    const int* lab = label + (long)b * 2 * Nn;
    float semsum = 0.0f;
    float3 p[EPB];
    int inst[EPB];
#pragma unroll
    for (int e = 0; e < EPB; ++e) {
        const int n    = n0 + e * THREADS + tid;
        const int cls  = lab[n];
        inst[e] = lab[Nn + n];
        const long rowb = (long)b * Nn + n;
        semsum += __builtin_nontemporal_load(&sem[rowb * Cn + cls]);
        p[e] = ((const float3*)points)[rowb];
        float* a = acc[rep];
        atomicAdd(&a[0 * 21 + inst[e]], p[e].x);
        atomicAdd(&a[1 * 21 + inst[e]], p[e].y);
        atomicAdd(&a[2 * 21 + inst[e]], p[e].z);
        atomicAdd(&a[3 * 21 + inst[e]], 1.0f);
    }
    __syncthreads();

    // flush: 8 replicas -> one global atomic per (k,f); 640 distinct addrs
    if (tid < Kn * 4) {
        const int k = tid >> 2, f = tid & 3;
        float v = 0.0f;
#pragma unroll
        for (int r = 0; r < NREP; ++r) v += acc[r][f * 21 + k];
        atomicAdd(&ws[WS_SEG + (b * Kn + k) * 4 + f], v);
    }

    // block-reduce semsum -> unique slot (plain store)
    float s1 = semsum;
#pragma unroll
    for (int off = 32; off > 0; off >>= 1) s1 += __shfl_down(s1, off);
    if (lane == 0) wsum[wave] = s1;
    __syncthreads();
    if (tid == 0) ws[WS_SEMP + bid] = wsum[0] + wsum[1] + wsum[2] + wsum[3];

    grid.sync();   // all segment bins complete

    // ---- phase 2: centers, then csv loss (points/inst held in registers) ----
    if (tid < Kn) {
        const float* s = ws + WS_SEG + (b * Kn + tid) * 4;
        const float inv = 1.0f / fmaxf(s[3], 1.0f);
        ctr[tid][0] = s[0] * inv;
        ctr[tid][1] = s[1] * inv;
        ctr[tid][2] = s[2] * inv;
    }
    __syncthreads();

    float lsum = 0.0f;
#pragma unroll
    for (int e = 0; e < EPB; ++e) {
        const int n    = n0 + e * THREADS + tid;
        const long rowb = (long)b * Nn + n;
        const float3 q = ((const float3*)pcsv)[rowb];
        const int k = inst[e];
        const float dx = ctr[k][0] - p[e].x;
        const float dy = ctr[k][1] - p[e].y;
        const float dz = ctr[k][2] - p[e].z;
        const float nd = sqrtf(dx * dx + dy * dy + dz * dz);
        const float w  = fminf(nd, 1.0f);
        const float ex = dx - q.x;
        const float ey = dy - q.y;
        const float ez = dz - q.z;
        lsum += sqrtf(ex * ex + ey * ey + ez * ez) * w;
    }
#pragma unroll
    for (int off = 32; off > 0; off >>= 1) lsum += __shfl_down(lsum, off);
    if (lane == 0) wsum[wave] = lsum;
    __syncthreads();
    if (tid == 0) ws[WS_CSVP + bid] = wsum[0] + wsum[1] + wsum[2] + wsum[3];

    grid.sync();   // all partials visible

    // ---- phase 3: block 0 reduces 2*GRID partials, writes the scalar ----
    if (bid == 0) {
        float s = 0.0f, c = 0.0f;
#pragma unroll
        for (int i = 0; i < GRID / THREADS; ++i) {
            s += ws[WS_SEMP + i * THREADS + tid];
            c += ws[WS_CSVP + i * THREADS + tid];
        }
#pragma unroll
        for (int off = 32; off > 0; off >>= 1) {
            s += __shfl_down(s, off);
            c += __shfl_down(c, off);
        }
        __shared__ float ssum[4], csum[4];
        if (lane == 0) { ssum[wave] = s; csum[wave] = c; }
        __syncthreads();
        if (tid == 0) {
            const float S = ssum[0] + ssum[1] + ssum[2] + ssum[3];
            const float C = csum[0] + csum[1] + csum[2] + csum[3];
            const float invBN = 1.0f / (float)((long)Bn * Nn);
            out[0] = -S * invBN + 0.2f * C * invBN;
        }
    }
}

extern "C" void kernel_launch(void* const* d_in, const int* in_sizes, int n_in,
                              void* d_out, int out_size, void* d_ws, size_t ws_size,
                              hipStream_t stream) {
    const float* points = (const float*)d_in[0];
    const float* sem    = (const float*)d_in[1];
    const float* pcsv   = (const float*)d_in[2];
    const int*   label  = (const int*)d_in[3];
    float* ws  = (float*)d_ws;
    float* out = (float*)d_out;

    void* args[] = { (void*)&points, (void*)&sem, (void*)&pcsv,
                     (void*)&label, (void*)&ws, (void*)&out };
    hipLaunchCooperativeKernel((const void*)loss_fused,
                               dim3(GRID), dim3(THREADS),
                               args, 0, stream);
}

// Round 7
// 157.012 us; speedup vs baseline: 2.6739x; 2.6739x over previous
//
#include <hip/hip_runtime.h>
#include <hip/hip_bf16.h>

// Problem constants (match reference setup_inputs)
#define Bn 8
#define Nn 131072
#define Cn 20
#define Kn 20

#define THREADS 256

// pass1 geometry
#define GRID1 1024
#define BPB1 (GRID1 / Bn)        // 128 blocks per batch
#define CHUNK1 (Nn / BPB1)       // 1024 points per block
#define EPB1 (CHUNK1 / THREADS)  // 4 per thread

// pass2 geometry
#define GRID2 1024
#define BPB2 (GRID2 / Bn)        // 128
#define CHUNK2 (Nn / BPB2)       // 1024
#define EPB2 (CHUNK2 / THREADS)  // 4

// LDS bin replication: 8 copies indexed by lane&7, field-major with pad.
// acc[r][f*21 + k]; stride 84 floats -> replica bank offsets 20r mod 32
// = {0,20,8,28,16,4,24,12}, all distinct.
#define NREP 8
#define RSTRIDE 84

// ws layout (floats). NO zeroing needed: every slot is plain-stored before read.
// binp transposed: ws[WS_BIN + o*GRID1 + bid], o = f*20+k (f: 0=x,1=y,2=z,3=cnt)
#define WS_BIN 0
#define WS_SEMP (80 * GRID1)             // [GRID1) per-block sem partials
#define WS_CSVP (WS_SEMP + GRID1)        // [GRID2) per-block csv partials

// Pass 1: sem-loss gather-sum + per-(b,k) point partial sums -> unique slots.
__global__ void __launch_bounds__(THREADS) loss_pass1(
    const float* __restrict__ points,
    const float* __restrict__ sem,
    const int* __restrict__ label,
    float* __restrict__ ws) {
    __shared__ float acc[NREP][RSTRIDE];
    __shared__ float wsum[4];

    const int tid  = threadIdx.x;
    const int wave = tid >> 6;
    const int lane = tid & 63;
    const int rep  = lane & (NREP - 1);
    const int bid  = blockIdx.x;

    for (int i = tid; i < NREP * RSTRIDE; i += THREADS) ((float*)acc)[i] = 0.0f;
    __syncthreads();

    const int b  = bid / BPB1;
    const int n0 = (bid % BPB1) * CHUNK1;
    const int* lab = label + (long)b * 2 * Nn;

    float semsum = 0.0f;
#pragma unroll
    for (int e = 0; e < EPB1; ++e) {
        const int n    = n0 + e * THREADS + tid;
        const int cls  = lab[n];
        const int inst = lab[Nn + n];
        const long rowb = (long)b * Nn + n;
        semsum += __builtin_nontemporal_load(&sem[rowb * Cn + cls]);
        const float3 p = ((const float3*)points)[rowb];
        float* a = acc[rep];
        atomicAdd(&a[0 * 21 + inst], p.x);
        atomicAdd(&a[1 * 21 + inst], p.y);
        atomicAdd(&a[2 * 21 + inst], p.z);
        atomicAdd(&a[3 * 21 + inst], 1.0f);
    }
    __syncthreads();

    // flush: sum 8 replicas -> unique per-block slot, transposed layout,
    // PLAIN stores (no atomics, no zero-init needed).
    if (tid < 80) {
        const int f = tid / 20, k = tid % 20;
        float v = 0.0f;
#pragma unroll
        for (int r = 0; r < NREP; ++r) v += acc[r][f * 21 + k];
        ws[WS_BIN + tid * GRID1 + bid] = v;
    }

    // block-reduce semsum -> unique slot
#pragma unroll
    for (int off = 32; off > 0; off >>= 1) semsum += __shfl_down(semsum, off);
    if (lane == 0) wsum[wave] = semsum;
    __syncthreads();
    if (tid == 0) ws[WS_SEMP + bid] = wsum[0] + wsum[1] + wsum[2] + wsum[3];
}

// Pass 2: each block reduces its batch's 128 bin partial-sets (contiguous
// 128-float runs per output, L2-resident), computes centers, then csv loss.
__global__ void __launch_bounds__(THREADS) loss_pass2(
    const float* __restrict__ points,
    const float* __restrict__ pcsv,
    const int* __restrict__ label,
    float* __restrict__ ws) {
    __shared__ float sums[80];
    __shared__ float ctr[Kn][3];
    __shared__ float wsum[4];

    const int tid  = threadIdx.x;
    const int wave = tid >> 6;
    const int lane = tid & 63;
    const int bid  = blockIdx.x;
    const int b    = bid / BPB2;

    // reduce bin partials: output o summed over this batch's 128 blocks
    if (tid < 80) {
        const float* src = ws + WS_BIN + tid * GRID1 + b * BPB1;
        float v = 0.0f;
#pragma unroll 8
        for (int j = 0; j < BPB1; ++j) v += src[j];
        sums[tid] = v;
    }
    __syncthreads();
    if (tid < Kn) {
        const float inv = 1.0f / fmaxf(sums[3 * 20 + tid], 1.0f);
        ctr[tid][0] = sums[0 * 20 + tid] * inv;
        ctr[tid][1] = sums[1 * 20 + tid] * inv;
        ctr[tid][2] = sums[2 * 20 + tid] * inv;
    }
    __syncthreads();

    const int n0 = (bid % BPB2) * CHUNK2;
    const int* inst_lab = label + (long)b * 2 * Nn + Nn;

    float lsum = 0.0f;
#pragma unroll
    for (int e = 0; e < EPB2; ++e) {
        const int n    = n0 + e * THREADS + tid;
        const int inst = inst_lab[n];
        const long rowb = (long)b * Nn + n;
        const float3 p = ((const float3*)points)[rowb];
        const float3 q = ((const float3*)pcsv)[rowb];
        const float dx = ctr[inst][0] - p.x;
        const float dy = ctr[inst][1] - p.y;
        const float dz = ctr[inst][2] - p.z;
        const float nd = sqrtf(dx * dx + dy * dy + dz * dz);
        const float w  = fminf(nd, 1.0f);
        const float ex = dx - q.x;
        const float ey = dy - q.y;
        const float ez = dz - q.z;
        lsum += sqrtf(ex * ex + ey * ey + ez * ez) * w;
    }

#pragma unroll
    for (int off = 32; off > 0; off >>= 1) lsum += __shfl_down(lsum, off);
    if (lane == 0) wsum[wave] = lsum;
    __syncthreads();
    if (tid == 0) ws[WS_CSVP + bid] = wsum[0] + wsum[1] + wsum[2] + wsum[3];
}

// Finalize: reduce per-block partials, write the scalar loss.
__global__ void __launch_bounds__(THREADS) loss_final(
    const float* __restrict__ ws, float* __restrict__ out) {
    __shared__ float ssum[4], csum[4];
    const int tid  = threadIdx.x;
    const int wave = tid >> 6;
    const int lane = tid & 63;

    float s = 0.0f, c = 0.0f;
#pragma unroll
    for (int i = 0; i < GRID1 / THREADS; ++i) s += ws[WS_SEMP + i * THREADS + tid];
#pragma unroll
    for (int i = 0; i < GRID2 / THREADS; ++i) c += ws[WS_CSVP + i * THREADS + tid];
#pragma unroll
    for (int off = 32; off > 0; off >>= 1) {
        s += __shfl_down(s, off);
        c += __shfl_down(c, off);
    }
    if (lane == 0) { ssum[wave] = s; csum[wave] = c; }
    __syncthreads();
    if (tid == 0) {
        const float S = ssum[0] + ssum[1] + ssum[2] + ssum[3];
        const float C = csum[0] + csum[1] + csum[2] + csum[3];
        const float invBN = 1.0f / (float)((long)Bn * Nn);
        out[0] = -S * invBN + 0.2f * C * invBN;
    }
}

extern "C" void kernel_launch(void* const* d_in, const int* in_sizes, int n_in,
                              void* d_out, int out_size, void* d_ws, size_t ws_size,
                              hipStream_t stream) {
    const float* points = (const float*)d_in[0];
    const float* sem    = (const float*)d_in[1];
    const float* pcsv   = (const float*)d_in[2];
    const int*   label  = (const int*)d_in[3];
    float* ws  = (float*)d_ws;
    float* out = (float*)d_out;

    loss_pass1<<<GRID1, THREADS, 0, stream>>>(points, sem, label, ws);
    loss_pass2<<<GRID2, THREADS, 0, stream>>>(points, pcsv, label, ws);
    loss_final<<<1, THREADS, 0, stream>>>(ws, out);
}